// Round 6
// baseline (172.369 us; speedup 1.0000x reference)
//
#include <hip/hip_runtime.h>
#include <hip/hip_bf16.h>
#include <cstdint>

typedef __attribute__((ext_vector_type(8)))  short s8b;     // 8 bf16
typedef __attribute__((ext_vector_type(4)))  short s4b;     // 4 bf16
typedef __attribute__((ext_vector_type(16))) float f16v;    // 32x32 MFMA acc
typedef __attribute__((ext_vector_type(4)))  unsigned u4v;

#define MFMA32(a,b,c) __builtin_amdgcn_mfma_f32_32x32x16_bf16((a),(b),(c),0,0,0)

#define OLDN   16384
#define NEWB   2048
#define DHEAD  256
#define NTOTAL 18432
#define NTILES 576                      // NTOTAL / 32
#define EXPSC  0.09016844005556021f    // (1/sqrt(256)) * log2(e)

static __device__ __forceinline__ short f2bf(float f) {
    unsigned u = __float_as_uint(f);
    unsigned r = (u + 0x7fffu + ((u >> 16) & 1u)) >> 16;   // RNE
    return (short)r;
}
// V slot permutation: slot s -> key within 32-tile (matches S^T C-layout reg order)
static __device__ __forceinline__ int slot_key(int s) {
    return (s & 3) + 8 * ((s >> 2) & 1) + 4 * ((s >> 3) & 1) + 16 * (s >> 4);
}

// async global -> LDS, 16 B per lane (global_load_lds_dwordx4)
static __device__ __forceinline__ void dma16(const void* g, void* l) {
    __builtin_amdgcn_global_load_lds((const __attribute__((address_space(1))) unsigned int*)g,
                                     (__attribute__((address_space(3))) unsigned int*)l,
                                     16, 0, 0);
}

// ---------- kernel 1: build fragment-order bf16 tile copies ----------
__global__ void cvt_kernel(const float* __restrict__ Kc, const float* __restrict__ kn,
                           const float* __restrict__ Vc, const float* __restrict__ vn,
                           s8b* __restrict__ Ksw, s8b* __restrict__ Vsw) {
    const int t   = blockIdx.x;
    const int tid = threadIdx.x;
    if (blockIdx.y == 0) {
#pragma unroll
        for (int i = 0; i < 4; ++i) {
            int chunk = tid + 256 * i;            // = b*64 + l
            int l = chunk & 63;
            int b = chunk >> 6;
            int row = 32 * t + (l & 31);
            int col = 16 * b + 8 * (l >> 5);
            const float* src = (row < OLDN) ? Kc + (size_t)row * DHEAD + col
                                            : kn + (size_t)(row - OLDN) * DHEAD + col;
            float4 f0 = *(const float4*)src;
            float4 f1 = *(const float4*)(src + 4);
            s8b o;
            o[0]=f2bf(f0.x); o[1]=f2bf(f0.y); o[2]=f2bf(f0.z); o[3]=f2bf(f0.w);
            o[4]=f2bf(f1.x); o[5]=f2bf(f1.y); o[6]=f2bf(f1.z); o[7]=f2bf(f1.w);
            Ksw[(size_t)t * 1024 + chunk] = o;
        }
    } else {
#pragma unroll
        for (int i = 0; i < 4; ++i) {
            int chunk = tid + 256 * i;
            int l = chunk & 63;
            int b = chunk >> 6;
            int m = 32 * (b >> 1) + (l & 31);
            int sbase = 16 * (b & 1) + 8 * (l >> 5);
            s8b o;
#pragma unroll
            for (int j = 0; j < 8; ++j) {
                int row = 32 * t + slot_key(sbase + j);
                float v = (row < OLDN) ? Vc[(size_t)row * DHEAD + m]
                                       : vn[(size_t)(row - OLDN) * DHEAD + m];
                o[j] = f2bf(v);
            }
            Vsw[(size_t)t * 1024 + chunk] = o;
        }
    }
}

// ---------- kernel 2: flash attention, pipelined S(t) || PV(t-1) ----------
// LDS: K0,K1 (16 KB each) + V0,V1,V2 (16 KB each) = 80 KB -> 2 blocks/CU
// grid = 16 * SPLIT blocks of 256 threads; wave owns 32 q-rows (BLOCK_Q = 128)
__global__ __launch_bounds__(256, 2)
void attn_kernel(const float* __restrict__ q,
                 const s8b* __restrict__ Ksw, const s8b* __restrict__ Vsw,
                 short* __restrict__ OPb, float* __restrict__ L, int SPLIT) {
    __shared__ __align__(16) short smem[5 * 8192];   // [K0|K1|V0|V1|V2]

    const int bx   = blockIdx.x;
    const int s    = bx % SPLIT;
    const int qb   = bx / SPLIT;
    const int q0   = qb * 128;
    const int tid  = threadIdx.x;
    const int w    = tid >> 6;
    const int lane = tid & 63;
    const int lc   = lane & 31;
    const int h    = lane >> 5;

    // Q fragments (B-operand), EXPSC folded in
    s8b qf[16];
    {
        const int qrow = q0 + 32 * w + lc;
        const float* qp = q + (size_t)qrow * DHEAD + 8 * h;
#pragma unroll
        for (int c = 0; c < 16; ++c) {
            float4 f0 = *(const float4*)(qp + 16 * c);
            float4 f1 = *(const float4*)(qp + 16 * c + 4);
            s8b o;
            o[0]=f2bf(f0.x*EXPSC); o[1]=f2bf(f0.y*EXPSC); o[2]=f2bf(f0.z*EXPSC); o[3]=f2bf(f0.w*EXPSC);
            o[4]=f2bf(f1.x*EXPSC); o[5]=f2bf(f1.y*EXPSC); o[6]=f2bf(f1.z*EXPSC); o[7]=f2bf(f1.w*EXPSC);
            qf[c] = o;
        }
    }

    f16v acc[8];
#pragma unroll
    for (int c = 0; c < 8; ++c)
#pragma unroll
        for (int r = 0; r < 16; ++r) acc[c][r] = 0.f;
    float lsum = 0.f;

    const int nt_total = (OLDN + q0 + 128) >> 5;
    const int tb  = nt_total / SPLIT;
    const int rem = nt_total % SPLIT;
    const int t0  = s * tb + (s < rem ? s : rem);
    const int tcnt = tb + (s < rem ? 1 : 0);
    const int tend = t0 + tcnt;
    const int qbase = OLDN + q0 + 32 * w;

    // staging: waves 0-1 stage K chunks, waves 2-3 stage V chunks (8 chunks each)
    const bool isK  = (w < 2);
    const int  seg  = isK ? (8 * w) * 512 : (8 * (w - 2)) * 512;
    const s8b* gbase = isK ? (Ksw + (size_t)(8 * w) * 64 + lane)
                           : (Vsw + (size_t)(8 * (w - 2)) * 64 + lane);
    const int loff = lane * 8;

    auto stage = [&](int tt) {
        const s8b* g = gbase + (size_t)tt * 1024;
        short* dst = isK ? (smem + (tt & 1) * 8192 + seg + loff)
                         : (smem + 16384 + (tt % 3) * 8192 + seg + loff);
#pragma unroll
        for (int i = 0; i < 8; ++i) dma16(g + i * 64, dst + i * 512);
    };

    // exp/mask/pack: sacc -> pf0/pf1 (+ lsum)
    s8b pf0, pf1;
    auto softmax_pack = [&](const f16v& sacc0, const f16v& sacc1, int kk) {
        const bool domask = (kk + 31 > qbase);
        unsigned pk[8];
#pragma unroll
        for (int i = 0; i < 8; ++i) {
            const int r0 = 2 * i, r1 = 2 * i + 1;
            float ev0 = __builtin_exp2f(sacc0[r0] + sacc1[r0]);
            float ev1 = __builtin_exp2f(sacc0[r1] + sacc1[r1]);
            if (domask) {
                if (kk + (r0 & 3) + 8 * (r0 >> 2) + 4 * h > qbase + lc) ev0 = 0.f;
                if (kk + (r1 & 3) + 8 * (r1 >> 2) + 4 * h > qbase + lc) ev1 = 0.f;
            }
            lsum += ev0 + ev1;
            pk[i] = __builtin_amdgcn_perm(__float_as_uint(ev1), __float_as_uint(ev0), 0x07060302u);
        }
        pf0 = __builtin_bit_cast(s8b, (u4v){pk[0], pk[1], pk[2], pk[3]});
        pf1 = __builtin_bit_cast(s8b, (u4v){pk[4], pk[5], pk[6], pk[7]});
    };

    // ---- prologue: stage t0, t0+1; drain ----
    stage(t0);
    stage(t0 + 1 < tend ? t0 + 1 : tend - 1);
    __syncthreads();

    // ---- peeled first iteration: S(t0) + exp, no PV ----
    {
        const short* kb = smem + (t0 & 1) * 8192 + loff;
        f16v s0, s1;
#pragma unroll
        for (int r = 0; r < 16; ++r) { s0[r] = 0.f; s1[r] = 0.f; }
#pragma unroll
        for (int c = 0; c < 8; ++c) {
            s8b k0 = *(const s8b*)(kb + (2 * c) * 512);
            s8b k1 = *(const s8b*)(kb + (2 * c + 1) * 512);
            s0 = MFMA32(k0, qf[2 * c],     s0);
            s1 = MFMA32(k1, qf[2 * c + 1], s1);
        }
        softmax_pack(s0, s1, t0 << 5);
        __syncthreads();
        stage(t0 + 2 < tend ? t0 + 2 : tend - 1);
    }

    // ---- steady loop: S(t) interleaved with PV(t-1) ----
    for (int t = t0 + 1; t < tend; ++t) {
        const short* kb = smem + (t & 1) * 8192 + loff;
        const short* vb = smem + 16384 + ((t - 1) % 3) * 8192 + loff;
        f16v s0, s1;
#pragma unroll
        for (int r = 0; r < 16; ++r) { s0[r] = 0.f; s1[r] = 0.f; }
#pragma unroll
        for (int c = 0; c < 8; ++c) {
            s8b k0 = *(const s8b*)(kb + (2 * c) * 512);
            s8b v0 = *(const s8b*)(vb + (2 * c) * 512);
            s8b k1 = *(const s8b*)(kb + (2 * c + 1) * 512);
            s8b v1 = *(const s8b*)(vb + (2 * c + 1) * 512);
            s0 = MFMA32(k0, qf[2 * c], s0);
            acc[c] = MFMA32(v0, pf0, acc[c]);
            s1 = MFMA32(k1, qf[2 * c + 1], s1);
            acc[c] = MFMA32(v1, pf1, acc[c]);
        }
        softmax_pack(s0, s1, t << 5);
        __syncthreads();                 // drains stage(t+1) issued one full iter ago
        stage(t + 2 < tend ? t + 2 : tend - 1);
    }

    // ---- epilogue: PV(tend-1) ----
    {
        const short* vb = smem + 16384 + ((tend - 1) % 3) * 8192 + loff;
#pragma unroll
        for (int c = 0; c < 8; ++c) {
            s8b v0 = *(const s8b*)(vb + (2 * c) * 512);
            s8b v1 = *(const s8b*)(vb + (2 * c + 1) * 512);
            acc[c] = MFMA32(v0, pf0, acc[c]);
            acc[c] = MFMA32(v1, pf1, acc[c]);
        }
    }

    // finalize l (other half-lane holds the other 16 keys of each q-column)
    lsum += __shfl_xor(lsum, 32);

    // write bf16 unnormalized partials + fp32 l
    const int qrow = q0 + 32 * w + lc;
    const size_t sbase = (size_t)s * NEWB;
    short* op_row = OPb + (sbase + qrow) * DHEAD;
#pragma unroll
    for (int c = 0; c < 8; ++c)
#pragma unroll
        for (int g = 0; g < 4; ++g) {
            s4b o4;
            o4[0] = f2bf(acc[c][4 * g]);
            o4[1] = f2bf(acc[c][4 * g + 1]);
            o4[2] = f2bf(acc[c][4 * g + 2]);
            o4[3] = f2bf(acc[c][4 * g + 3]);
            *(s4b*)(op_row + 32 * c + 8 * g + 4 * h) = o4;
        }
    if (h == 0) L[sbase + qrow] = lsum;
}

// ---------- kernel 3: split-K combine (bf16 partials, fp32 l) ----------
__global__ void combine_kernel(const short* __restrict__ OPb, const float* __restrict__ L,
                               float* __restrict__ out, int SPLIT) {
    const int row = blockIdx.x;
    const int col = threadIdx.x;
    float num = 0.f, den = 0.f;
    for (int s = 0; s < SPLIT; ++s) {
        size_t r = (size_t)s * NEWB + row;
        unsigned u = (unsigned)(unsigned short)OPb[r * DHEAD + col];
        num += __uint_as_float(u << 16);
        den += L[r];
    }
    out[(size_t)row * DHEAD + col] = num / den;
}

// ---------- launch ----------
extern "C" void kernel_launch(void* const* d_in, const int* in_sizes, int n_in,
                              void* d_out, int out_size, void* d_ws, size_t ws_size,
                              hipStream_t stream) {
    const float* q  = (const float*)d_in[0];
    const float* kn = (const float*)d_in[1];
    const float* vn = (const float*)d_in[2];
    const float* Kc = (const float*)d_in[3];
    const float* Vc = (const float*)d_in[4];
    float* out = (float*)d_out;

    char* ws = (char*)d_ws;
    const size_t KB_BYTES = (size_t)NTOTAL * DHEAD * 2;   // 9,437,184 per array
    s8b* Ksw = (s8b*)(ws);
    s8b* Vsw = (s8b*)(ws + KB_BYTES);
    const size_t PART_BASE = 2 * KB_BYTES;

    const size_t per_split = (size_t)NEWB * DHEAD * 2 + (size_t)NEWB * 4;  // bf16 OP + fp32 L
    size_t avail = (ws_size > PART_BASE) ? (ws_size - PART_BASE) : 0;
    int SPLIT = (int)(avail / per_split);
    if (SPLIT > 32) SPLIT = 32;    // grid 512 = 2 blocks/CU
    if (SPLIT < 1)  SPLIT = 1;

    short* OPb = (short*)(ws + PART_BASE);
    float* L   = (float*)(ws + PART_BASE + (size_t)SPLIT * NEWB * DHEAD * 2);

    cvt_kernel<<<dim3(NTILES, 2), 256, 0, stream>>>(Kc, kn, Vc, vn, Ksw, Vsw);
    attn_kernel<<<16 * SPLIT, 256, 0, stream>>>(q, Ksw, Vsw, OPb, L, SPLIT);
    combine_kernel<<<NEWB, 256, 0, stream>>>(OPb, L, out, SPLIT);
}

// Round 7
// 167.176 us; speedup vs baseline: 1.0311x; 1.0311x over previous
//
#include <hip/hip_runtime.h>
#include <hip/hip_bf16.h>
#include <cstdint>

typedef __attribute__((ext_vector_type(8)))  short s8b;     // 8 bf16
typedef __attribute__((ext_vector_type(4)))  short s4b;     // 4 bf16
typedef __attribute__((ext_vector_type(16))) float f16v;    // 32x32 MFMA acc
typedef __attribute__((ext_vector_type(4)))  unsigned u4v;

#define MFMA32(a,b,c) __builtin_amdgcn_mfma_f32_32x32x16_bf16((a),(b),(c),0,0,0)

#define OLDN   16384
#define NEWB   2048
#define DHEAD  256
#define NTOTAL 18432
#define NTILES 576                      // NTOTAL / 32
#define EXPSC  0.09016844005556021f    // (1/sqrt(256)) * log2(e)

// LDS layout (shorts): K bufs 2x8192 | V bufs 2x8192 | P bufs 2x4096  = 80 KB
#define KOFF(b) ((b) * 8192)
#define VOFF(b) (16384 + (b) * 8192)
#define POFF(b) (32768 + (b) * 4096)

static __device__ __forceinline__ short f2bf(float f) {
    unsigned u = __float_as_uint(f);
    unsigned r = (u + 0x7fffu + ((u >> 16) & 1u)) >> 16;   // RNE
    return (short)r;
}
// V slot permutation: slot s -> key within 32-tile (matches S^T C-layout reg order)
static __device__ __forceinline__ int slot_key(int s) {
    return (s & 3) + 8 * ((s >> 2) & 1) + 4 * ((s >> 3) & 1) + 16 * (s >> 4);
}

// async global -> LDS, 16 B per lane (global_load_lds_dwordx4)
static __device__ __forceinline__ void dma16(const void* g, void* l) {
    __builtin_amdgcn_global_load_lds((const __attribute__((address_space(1))) unsigned int*)g,
                                     (__attribute__((address_space(3))) unsigned int*)l,
                                     16, 0, 0);
}

// ---------- kernel 1: build fragment-order bf16 tile copies ----------
__global__ void cvt_kernel(const float* __restrict__ Kc, const float* __restrict__ kn,
                           const float* __restrict__ Vc, const float* __restrict__ vn,
                           s8b* __restrict__ Ksw, s8b* __restrict__ Vsw) {
    const int t   = blockIdx.x;
    const int tid = threadIdx.x;
    if (blockIdx.y == 0) {
#pragma unroll
        for (int i = 0; i < 4; ++i) {
            int chunk = tid + 256 * i;            // = b*64 + l
            int l = chunk & 63;
            int b = chunk >> 6;
            int row = 32 * t + (l & 31);
            int col = 16 * b + 8 * (l >> 5);
            const float* src = (row < OLDN) ? Kc + (size_t)row * DHEAD + col
                                            : kn + (size_t)(row - OLDN) * DHEAD + col;
            float4 f0 = *(const float4*)src;
            float4 f1 = *(const float4*)(src + 4);
            s8b o;
            o[0]=f2bf(f0.x); o[1]=f2bf(f0.y); o[2]=f2bf(f0.z); o[3]=f2bf(f0.w);
            o[4]=f2bf(f1.x); o[5]=f2bf(f1.y); o[6]=f2bf(f1.z); o[7]=f2bf(f1.w);
            Ksw[(size_t)t * 1024 + chunk] = o;
        }
    } else {
#pragma unroll
        for (int i = 0; i < 4; ++i) {
            int chunk = tid + 256 * i;
            int l = chunk & 63;
            int b = chunk >> 6;
            int m = 32 * (b >> 1) + (l & 31);
            int sbase = 16 * (b & 1) + 8 * (l >> 5);
            s8b o;
#pragma unroll
            for (int j = 0; j < 8; ++j) {
                int row = 32 * t + slot_key(sbase + j);
                float v = (row < OLDN) ? Vc[(size_t)row * DHEAD + m]
                                       : vn[(size_t)(row - OLDN) * DHEAD + m];
                o[j] = f2bf(v);
            }
            Vsw[(size_t)t * 1024 + chunk] = o;
        }
    }
}

// ---------- kernel 2: wave-specialized flash attention ----------
// 768 threads = 12 waves: waves 0-3 = S (one per 32-q group), waves 4-11 = PV
// (group g = w&3, D-half hd = (w>>2)-1). 3 waves/SIMD, 1 block/CU.
__global__ __launch_bounds__(768, 3)
void attn_kernel(const float* __restrict__ q,
                 const s8b* __restrict__ Ksw, const s8b* __restrict__ Vsw,
                 short* __restrict__ OPb, float* __restrict__ L, int SPLIT) {
    __shared__ __align__(16) short smem[40960];   // 80 KB

    const int bx   = blockIdx.x;
    const int s    = bx % SPLIT;
    const int qb   = bx / SPLIT;
    const int q0   = qb * 128;
    const int tid  = threadIdx.x;
    const int w    = tid >> 6;
    const int lane = tid & 63;
    const int lc   = lane & 31;
    const int h    = lane >> 5;
    const bool isS = (w < 4);
    const int  g   = w & 3;
    const int  loff = lane * 8;

    const int nt_total = (OLDN + q0 + 128) >> 5;
    const int tb_ = nt_total / SPLIT;
    const int rem = nt_total % SPLIT;
    const int t0  = s * tb_ + (s < rem ? s : rem);
    const int tcnt = tb_ + (s < rem ? 1 : 0);
    const int tend = t0 + tcnt;

    if (isS) {
        // ================= S-wave: S = K Q^T, softmax, publish P =================
        const int qbase = OLDN + q0 + 32 * g;
        float lsum = 0.f;

        s8b qf[16];
        {
            const int qrow = q0 + 32 * g + lc;
            const float* qp = q + (size_t)qrow * DHEAD + 8 * h;
#pragma unroll
            for (int c = 0; c < 16; ++c) {
                float4 f0 = *(const float4*)(qp + 16 * c);
                float4 f1 = *(const float4*)(qp + 16 * c + 4);
                s8b o;
                o[0]=f2bf(f0.x*EXPSC); o[1]=f2bf(f0.y*EXPSC); o[2]=f2bf(f0.z*EXPSC); o[3]=f2bf(f0.w*EXPSC);
                o[4]=f2bf(f1.x*EXPSC); o[5]=f2bf(f1.y*EXPSC); o[6]=f2bf(f1.z*EXPSC); o[7]=f2bf(f1.w*EXPSC);
                qf[c] = o;
            }
        }

        // stage K chunks 4g..4g+3 of tile t into K buf
        auto stageK = [&](int t, int buf) {
            const s8b* gs = Ksw + (size_t)t * 1024 + (4 * g) * 64 + lane;
            short* dst = smem + KOFF(buf) + (4 * g) * 512 + loff;
#pragma unroll
            for (int i = 0; i < 4; ++i) dma16(gs + i * 64, dst + i * 512);
        };

        stageK(t0, 0);
        __syncthreads();

        for (int b = 0; b < tcnt; ++b) {
            const int t = t0 + b;
            const int be = b & 1;
            if (t + 1 < tend) stageK(t + 1, be ^ 1);

            const short* kb = smem + KOFF(be) + loff;
            f16v s0, s1;
#pragma unroll
            for (int r = 0; r < 16; ++r) { s0[r] = 0.f; s1[r] = 0.f; }
#pragma unroll
            for (int c = 0; c < 8; ++c) {
                s8b k0 = *(const s8b*)(kb + (2 * c) * 512);
                s8b k1 = *(const s8b*)(kb + (2 * c + 1) * 512);
                s0 = MFMA32(k0, qf[2 * c],     s0);
                s1 = MFMA32(k1, qf[2 * c + 1], s1);
            }

            const int kk = t << 5;
            const bool domask = (kk + 31 > qbase);
            unsigned pk[8];
#pragma unroll
            for (int i = 0; i < 8; ++i) {
                const int r0 = 2 * i, r1 = 2 * i + 1;
                float ev0 = __builtin_exp2f(s0[r0] + s1[r0]);
                float ev1 = __builtin_exp2f(s0[r1] + s1[r1]);
                if (domask) {
                    if (kk + (r0 & 3) + 8 * (r0 >> 2) + 4 * h > qbase + lc) ev0 = 0.f;
                    if (kk + (r1 & 3) + 8 * (r1 >> 2) + 4 * h > qbase + lc) ev1 = 0.f;
                }
                lsum += ev0 + ev1;
                pk[i] = __builtin_amdgcn_perm(__float_as_uint(ev1), __float_as_uint(ev0), 0x07060302u);
            }
            s8b pf0 = __builtin_bit_cast(s8b, (u4v){pk[0], pk[1], pk[2], pk[3]});
            s8b pf1 = __builtin_bit_cast(s8b, (u4v){pk[4], pk[5], pk[6], pk[7]});

            short* pw = smem + POFF(be) + g * 1024 + loff;
            *(s8b*)pw         = pf0;
            *(s8b*)(pw + 512) = pf1;

            __syncthreads();
        }

        lsum += __shfl_xor(lsum, 32);
        if (h == 0) L[(size_t)s * NEWB + q0 + 32 * g + lc] = lsum;

    } else {
        // ================= PV-wave: O^T(half-D) += V^T P^T =================
        const int hd = (w >> 2) - 1;            // 0 or 1: dims 128*hd..128*hd+127
        f16v acc[4];
#pragma unroll
        for (int j = 0; j < 4; ++j)
#pragma unroll
            for (int r = 0; r < 16; ++r) acc[j][r] = 0.f;

        const int c0 = 2 * (w - 4);             // this wave's 2 V chunks to stage
        auto stageV = [&](int t, int buf) {
            const s8b* gs = Vsw + (size_t)t * 1024 + c0 * 64 + lane;
            short* dst = smem + VOFF(buf) + c0 * 512 + loff;
#pragma unroll
            for (int i = 0; i < 2; ++i) dma16(gs + i * 64, dst + i * 512);
        };

        __syncthreads();                        // match S prologue barrier

        for (int b = 0; b < tcnt; ++b) {
            const int t = t0 + b;
            const int be = b & 1;
            stageV(t, be);

            if (b > 0) {
                const short* vb = smem + VOFF(be ^ 1) + loff;
                const short* pr = smem + POFF(be ^ 1) + g * 1024 + loff;
                s8b p0 = *(const s8b*)pr;
                s8b p1 = *(const s8b*)(pr + 512);
#pragma unroll
                for (int j = 0; j < 4; ++j) {
                    const int c = 4 * hd + j;
                    s8b v0 = *(const s8b*)(vb + (2 * c) * 512);
                    s8b v1 = *(const s8b*)(vb + (2 * c + 1) * 512);
                    acc[j] = MFMA32(v0, p0, acc[j]);
                    acc[j] = MFMA32(v1, p1, acc[j]);
                }
            }
            __syncthreads();
        }

        // epilogue: PV for the last tile
        {
            const int be = (tcnt - 1) & 1;
            const short* vb = smem + VOFF(be) + loff;
            const short* pr = smem + POFF(be) + g * 1024 + loff;
            s8b p0 = *(const s8b*)pr;
            s8b p1 = *(const s8b*)(pr + 512);
#pragma unroll
            for (int j = 0; j < 4; ++j) {
                const int c = 4 * hd + j;
                s8b v0 = *(const s8b*)(vb + (2 * c) * 512);
                s8b v1 = *(const s8b*)(vb + (2 * c + 1) * 512);
                acc[j] = MFMA32(v0, p0, acc[j]);
                acc[j] = MFMA32(v1, p1, acc[j]);
            }
        }

        // write bf16 unnormalized partials for this D-half
        const int qrow = q0 + 32 * g + lc;
        short* op_row = OPb + ((size_t)s * NEWB + qrow) * DHEAD;
#pragma unroll
        for (int j = 0; j < 4; ++j) {
            const int c = 4 * hd + j;
#pragma unroll
            for (int gq = 0; gq < 4; ++gq) {
                s4b o4;
                o4[0] = f2bf(acc[j][4 * gq]);
                o4[1] = f2bf(acc[j][4 * gq + 1]);
                o4[2] = f2bf(acc[j][4 * gq + 2]);
                o4[3] = f2bf(acc[j][4 * gq + 3]);
                *(s4b*)(op_row + 32 * c + 8 * gq + 4 * h) = o4;
            }
        }
    }
}

// ---------- kernel 3: split-K combine (bf16 partials, fp32 l) ----------
__global__ void combine_kernel(const short* __restrict__ OPb, const float* __restrict__ L,
                               float* __restrict__ out, int SPLIT) {
    const int row = blockIdx.x;
    const int col = threadIdx.x;
    float num = 0.f, den = 0.f;
    for (int s = 0; s < SPLIT; ++s) {
        size_t r = (size_t)s * NEWB + row;
        unsigned u = (unsigned)(unsigned short)OPb[r * DHEAD + col];
        num += __uint_as_float(u << 16);
        den += L[r];
    }
    out[(size_t)row * DHEAD + col] = num / den;
}

// ---------- launch ----------
extern "C" void kernel_launch(void* const* d_in, const int* in_sizes, int n_in,
                              void* d_out, int out_size, void* d_ws, size_t ws_size,
                              hipStream_t stream) {
    const float* q  = (const float*)d_in[0];
    const float* kn = (const float*)d_in[1];
    const float* vn = (const float*)d_in[2];
    const float* Kc = (const float*)d_in[3];
    const float* Vc = (const float*)d_in[4];
    float* out = (float*)d_out;

    char* ws = (char*)d_ws;
    const size_t KB_BYTES = (size_t)NTOTAL * DHEAD * 2;   // 9,437,184 per array
    s8b* Ksw = (s8b*)(ws);
    s8b* Vsw = (s8b*)(ws + KB_BYTES);
    const size_t PART_BASE = 2 * KB_BYTES;

    const size_t per_split = (size_t)NEWB * DHEAD * 2 + (size_t)NEWB * 4;  // bf16 OP + fp32 L
    size_t avail = (ws_size > PART_BASE) ? (ws_size - PART_BASE) : 0;
    int SPLIT = (int)(avail / per_split);
    if (SPLIT > 16) SPLIT = 16;    // grid 256 = 1 block/CU (768 threads, 12 waves)
    if (SPLIT < 1)  SPLIT = 1;

    short* OPb = (short*)(ws + PART_BASE);
    float* L   = (float*)(ws + PART_BASE + (size_t)SPLIT * NEWB * DHEAD * 2);

    cvt_kernel<<<dim3(NTILES, 2), 256, 0, stream>>>(Kc, kn, Vc, vn, Ksw, Vsw);
    attn_kernel<<<16 * SPLIT, 768, 0, stream>>>(q, Ksw, Vsw, OPb, L, SPLIT);
    combine_kernel<<<NEWB, 256, 0, stream>>>(OPb, L, out, SPLIT);
}